// Round 1
// baseline (99.419 us; speedup 1.0000x reference)
//
#include <hip/hip_runtime.h>
#include <math.h>

#define NROWS 16384
#define DDIM  128
#define JCHUNK 2048

__device__ __forceinline__ float wave_reduce_sum(float v) {
    #pragma unroll
    for (int m = 32; m >= 1; m >>= 1) v += __shfl_xor(v, m, 64);
    return v;
}

// ws layout (floats):
//   [0..1]                acc: loss_sum, weight_sum
//   [2]                   inv proto norm
//   [256 .. 256+N)        logits
//   [256+N .. 256+2N)     denom
//   [256+2N .. 256+4N)    te pairs: (time_j, exp(logit_j)) interleaved

__global__ void k_zero(float* __restrict__ denom, float* __restrict__ acc) {
    int i = blockIdx.x * blockDim.x + threadIdx.x;
    if (i < NROWS) denom[i] = 0.0f;
    if (i < 3) acc[i] = 0.0f;
}

__global__ void k_proto_norm(const float* __restrict__ proto, float* __restrict__ ws_f) {
    int lane = threadIdx.x;            // 64 threads, lane loads 2 elems
    float2 p = ((const float2*)proto)[lane];
    float s = p.x * p.x + p.y * p.y;
    s = wave_reduce_sum(s);
    if (lane == 0) ws_f[2] = 1.0f / fmaxf(sqrtf(s), 1e-12f);
}

__global__ __launch_bounds__(256) void k_logits(
    const float* __restrict__ feats, const float* __restrict__ proto,
    const float* __restrict__ times, const float* __restrict__ ws_f,
    float* __restrict__ logits, float* __restrict__ te)
{
    int wave = threadIdx.x >> 6, lane = threadIdx.x & 63;
    int row = blockIdx.x * 4 + wave;   // one wave per row
    float2 f = ((const float2*)feats)[row * 64 + lane];
    float2 p = ((const float2*)proto)[lane];
    float d  = f.x * p.x + f.y * p.y;
    float n2 = f.x * f.x + f.y * f.y;
    d  = wave_reduce_sum(d);
    n2 = wave_reduce_sum(n2);
    if (lane == 0) {
        float sp    = ws_f[2];
        float invfn = 1.0f / fmaxf(sqrtf(n2), 1e-12f);
        float logit = (d * sp * invfn) / 0.07f;
        logits[row]     = logit;
        te[2 * row]     = times[row];
        te[2 * row + 1] = expf(logit);
    }
}

// denom[i] = sum_j exp(logit_j) * (times[j] >= times[i])
// grid: (NROWS/256 i-chunks, NROWS/JCHUNK j-chunks); each block stages
// JCHUNK (t,e) pairs (16KB) into LDS; every thread owns one i.
__global__ __launch_bounds__(256) void k_denom(
    const float* __restrict__ times, const float* __restrict__ te,
    float* __restrict__ denom)
{
    __shared__ float4 sh[JCHUNK / 2];  // 1024 float4 = 16 KB
    int t = threadIdx.x;
    int i = blockIdx.x * 256 + t;
    const float4* src = (const float4*)(te + (size_t)blockIdx.y * JCHUNK * 2);
    #pragma unroll
    for (int k = 0; k < 4; ++k) sh[t + 256 * k] = src[t + 256 * k];
    __syncthreads();
    float ti  = times[i];
    float acc = 0.0f;
    #pragma unroll 8
    for (int jj = 0; jj < JCHUNK / 2; ++jj) {
        float4 v = sh[jj];             // broadcast read: conflict-free
        acc += (v.x >= ti) ? v.y : 0.0f;
        acc += (v.z >= ti) ? v.w : 0.0f;
    }
    atomicAdd(&denom[i], acc);
}

__global__ __launch_bounds__(256) void k_loss(
    const float* __restrict__ logits, const float* __restrict__ denom,
    const int* __restrict__ events, const float* __restrict__ w,
    float* __restrict__ acc)
{
    int i = blockIdx.x * 256 + threadIdx.x;
    float ev = (float)events[i];
    float wv = ev * w[i];
    float l  = logits[i];
    float ld = logf(denom[i] + 1e-8f);
    float loss = -(l - ld) * wv;
    loss = wave_reduce_sum(loss);
    wv   = wave_reduce_sum(wv);
    __shared__ float s1[4], s2[4];
    int wave = threadIdx.x >> 6, lane = threadIdx.x & 63;
    if (lane == 0) { s1[wave] = loss; s2[wave] = wv; }
    __syncthreads();
    if (threadIdx.x == 0) {
        atomicAdd(&acc[0], s1[0] + s1[1] + s1[2] + s1[3]);
        atomicAdd(&acc[1], s2[0] + s2[1] + s2[2] + s2[3]);
    }
}

__global__ void k_final(const float* __restrict__ acc, float* __restrict__ out) {
    out[0] = acc[0] / (acc[1] + 1e-8f);
}

extern "C" void kernel_launch(void* const* d_in, const int* in_sizes, int n_in,
                              void* d_out, int out_size, void* d_ws, size_t ws_size,
                              hipStream_t stream) {
    const float* feats  = (const float*)d_in[0];
    const float* times  = (const float*)d_in[1];
    const int*   events = (const int*)d_in[2];
    const float* w      = (const float*)d_in[3];
    const float* proto  = (const float*)d_in[4];
    float* out  = (float*)d_out;
    float* ws_f = (float*)d_ws;

    float* acc    = ws_f;
    float* logits = ws_f + 256;
    float* denom  = ws_f + 256 + NROWS;
    float* te     = ws_f + 256 + 2 * NROWS;

    k_zero<<<(NROWS + 255) / 256, 256, 0, stream>>>(denom, acc);
    k_proto_norm<<<1, 64, 0, stream>>>(proto, ws_f);
    k_logits<<<NROWS / 4, 256, 0, stream>>>(feats, proto, times, ws_f, logits, te);
    k_denom<<<dim3(NROWS / 256, NROWS / JCHUNK), 256, 0, stream>>>(times, te, denom);
    k_loss<<<NROWS / 256, 256, 0, stream>>>(logits, denom, events, w, acc);
    k_final<<<1, 1, 0, stream>>>(acc, out);
}